// Round 3
// baseline (544.046 us; speedup 1.0000x reference)
//
#include <hip/hip_runtime.h>

#define BB 16
#define SS 4096
#define HH 1024
#define NCHUNK 64   // chunks per batch row; 64 rows per chunk

__device__ __forceinline__ float fast_tanh(float x) {
    x = fminf(fmaxf(x, -15.0f), 15.0f);
    float e = __expf(-2.0f * x);
    return (1.0f - e) * __builtin_amdgcn_rcpf(1.0f + e);
}

__device__ __forceinline__ float wave_reduce_sum(float v) {
#pragma unroll
    for (int off = 32; off > 0; off >>= 1) v += __shfl_xor(v, off, 64);
    return v;
}

__device__ __forceinline__ float wave_reduce_max(float v) {
#pragma unroll
    for (int off = 32; off > 0; off >>= 1) v = fmaxf(v, __shfl_xor(v, off, 64));
    return v;
}

// K1: dec_fea[b,h] = sum_k s_t_hat[b,k] * W_dec[h,k] + b_dec[h]
__global__ __launch_bounds__(256) void dec_fea_kernel(
    const float* __restrict__ s_t_hat, const float* __restrict__ W_dec,
    const float* __restrict__ b_dec, float* __restrict__ dec_fea)
{
    int wave = (blockIdx.x * blockDim.x + threadIdx.x) >> 6;  // 0..B*H-1
    int lane = threadIdx.x & 63;
    int b = wave >> 10;
    int h = wave & (HH - 1);
    const float4* st4 = (const float4*)(s_t_hat + (size_t)b * HH);
    const float4* wd4 = (const float4*)(W_dec + (size_t)h * HH);
    float acc = 0.0f;
#pragma unroll
    for (int j = 0; j < 4; ++j) {
        int idx = lane + 64 * j;
        float4 a = st4[idx];
        float4 w = wd4[idx];
        acc += a.x * w.x + a.y * w.y + a.z * w.z + a.w * w.w;
    }
    acc = wave_reduce_sum(acc);
    if (lane == 0) dec_fea[wave] = acc + b_dec[h];
}

// K2: scores for one 64-row chunk per block (4 waves x 16 rows), plus
// per-chunk softmax stats (m, sum_e, sum_t) relative to chunk max.
// dec_fea/W_c/v fragments loaded ONCE per wave into registers.
__global__ __launch_bounds__(256) void scores_stats_kernel(
    const float* __restrict__ ef, const float* __restrict__ dec_fea,
    const float* __restrict__ cov, const float* __restrict__ W_c,
    const float* __restrict__ v, const float* __restrict__ mask,
    float* __restrict__ scores, float* __restrict__ stat_m,
    float* __restrict__ stat_se, float* __restrict__ stat_st)
{
    int b = blockIdx.y;
    int chunk = blockIdx.x;
    int s0 = chunk * 64;
    int wid = threadIdx.x >> 6;
    int lane = threadIdx.x & 63;
    __shared__ float sc[64];

    const float4* de4 = (const float4*)(dec_fea + (size_t)b * HH);
    const float4* wc4 = (const float4*)W_c;
    const float4* v4  = (const float4*)v;
    float4 d[4], w[4], vv[4];
#pragma unroll
    for (int j = 0; j < 4; ++j) {
        int idx = lane + 64 * j;
        d[j] = de4[idx]; w[j] = wc4[idx]; vv[j] = v4[idx];
    }

    for (int r = 0; r < 16; ++r) {
        int s = s0 + wid * 16 + r;
        size_t row = (size_t)b * SS + s;
        float cv = cov[row];
        const float4* ef4 = (const float4*)(ef + row * HH);
        float acc = 0.0f;
#pragma unroll
        for (int j = 0; j < 4; ++j) {
            float4 x = ef4[lane + 64 * j];
            acc += fast_tanh(x.x + d[j].x + cv * w[j].x) * vv[j].x;
            acc += fast_tanh(x.y + d[j].y + cv * w[j].y) * vv[j].y;
            acc += fast_tanh(x.z + d[j].z + cv * w[j].z) * vv[j].z;
            acc += fast_tanh(x.w + d[j].w + cv * w[j].w) * vv[j].w;
        }
        acc = wave_reduce_sum(acc);
        if (lane == 0) { sc[wid * 16 + r] = acc; scores[row] = acc; }
    }
    __syncthreads();

    if (threadIdx.x < 64) {  // wave 0: one lane per row of the chunk
        float s_val = sc[lane];
        float mk = mask[(size_t)b * SS + s0 + lane];
        float m = wave_reduce_max(s_val);
        float e = __expf(s_val - m);
        float se = wave_reduce_sum(e);
        float st = wave_reduce_sum(e * mk);
        if (lane == 0) {
            int idx = b * NCHUNK + chunk;
            stat_m[idx] = m; stat_se[idx] = se; stat_st[idx] = st;
        }
    }
}

// K3: merge chunk stats per batch row -> global max M and final scale alpha
// 1 block x 1024 threads; wave b handles batch b, lane = chunk
__global__ __launch_bounds__(1024) void stats_merge_kernel(
    const float* __restrict__ stat_m, const float* __restrict__ stat_se,
    const float* __restrict__ stat_st, float* __restrict__ Mb,
    float* __restrict__ alpha_b)
{
    int b = threadIdx.x >> 6, lane = threadIdx.x & 63;
    int idx = b * NCHUNK + lane;
    float m = stat_m[idx], se = stat_se[idx], st = stat_st[idx];
    float M = wave_reduce_max(m);
    float scale = __expf(m - M);
    float de = wave_reduce_sum(se * scale);
    float dt = wave_reduce_sum(st * scale);
    if (lane == 0) {
        // reference order: attn = (e*mask/de) / (dt/de + 1e-20)
        float inv = 1.0f / de;
        alpha_b[b] = inv * (1.0f / (dt * inv + 1e-20f));
        Mb[b] = M;
    }
}

// K4: final weights from scores (global M, alpha), write attn1/attn2,
// accumulate per-chunk context partial.
__global__ __launch_bounds__(256) void context_kernel(
    const float* __restrict__ eo, const float* __restrict__ scores,
    const float* __restrict__ mask, const float* __restrict__ Mb,
    const float* __restrict__ alpha_b, float* __restrict__ attn1,
    float* __restrict__ attn2, float* __restrict__ partials)
{
    int b = blockIdx.y, chunk = blockIdx.x, s0 = chunk * 64;
    int tid = threadIdx.x;
    __shared__ float wsh[64];
    float M = Mb[b], a = alpha_b[b];
    if (tid < 64) {
        size_t s = (size_t)b * SS + s0 + tid;
        float wv = __expf(scores[s] - M) * mask[s] * a;
        wsh[tid] = wv;
        attn1[s] = wv;
        attn2[s] = wv;
    }
    __syncthreads();
    const float4* eo4 = (const float4*)(eo + ((size_t)b * SS + s0) * HH);
    float4 acc = {0.0f, 0.0f, 0.0f, 0.0f};
#pragma unroll 8
    for (int s = 0; s < 64; ++s) {
        float wv = wsh[s];
        float4 x = eo4[(size_t)s * 256 + tid];
        acc.x += wv * x.x; acc.y += wv * x.y;
        acc.z += wv * x.z; acc.w += wv * x.w;
    }
    ((float4*)(partials + ((size_t)chunk * BB + b) * HH))[tid] = acc;
}

// K5: c_t[b,h] = sum_chunk partials[chunk][b][h]
// 64 blocks x 256 threads: block = (b, quarter of H), thread owns one h
__global__ __launch_bounds__(256) void context_reduce_kernel(
    const float* __restrict__ partials, float* __restrict__ c_t)
{
    int b = blockIdx.x >> 2;
    int h = (blockIdx.x & 3) * 256 + threadIdx.x;
    float acc = 0.0f;
#pragma unroll
    for (int c = 0; c < NCHUNK; ++c)
        acc += partials[((size_t)c * BB + b) * HH + h];
    c_t[(size_t)b * HH + h] = acc;
}

extern "C" void kernel_launch(void* const* d_in, const int* in_sizes, int n_in,
                              void* d_out, int out_size, void* d_ws, size_t ws_size,
                              hipStream_t stream)
{
    const float* s_t_hat  = (const float*)d_in[0];
    const float* enc_out  = (const float*)d_in[1];
    const float* enc_feat = (const float*)d_in[2];
    const float* mask     = (const float*)d_in[3];
    const float* cov      = (const float*)d_in[4];
    const float* W_dec    = (const float*)d_in[5];
    const float* b_dec    = (const float*)d_in[6];
    const float* W_c      = (const float*)d_in[7];
    const float* v        = (const float*)d_in[8];

    float* out    = (float*)d_out;
    float* c_t    = out;                    // B*H
    float* attn1  = out + BB * HH;          // B*S
    float* attn2  = attn1 + BB * SS;        // B*S
    float* scores = attn2 + BB * SS;        // B*S

    float* dec_fea  = (float*)d_ws;                     // B*H
    float* partials = dec_fea + BB * HH;                // NCHUNK*B*H (4 MB)
    float* stat_m   = partials + NCHUNK * BB * HH;      // B*NCHUNK
    float* stat_se  = stat_m + BB * NCHUNK;
    float* stat_st  = stat_se + BB * NCHUNK;
    float* Mb       = stat_st + BB * NCHUNK;            // B
    float* alpha_b  = Mb + BB;                          // B

    dec_fea_kernel<<<dim3(BB * HH / 4), 256, 0, stream>>>(
        s_t_hat, W_dec, b_dec, dec_fea);
    scores_stats_kernel<<<dim3(NCHUNK, BB), 256, 0, stream>>>(
        enc_feat, dec_fea, cov, W_c, v, mask, scores, stat_m, stat_se, stat_st);
    stats_merge_kernel<<<dim3(1), 1024, 0, stream>>>(
        stat_m, stat_se, stat_st, Mb, alpha_b);
    context_kernel<<<dim3(NCHUNK, BB), 256, 0, stream>>>(
        enc_out, scores, mask, Mb, alpha_b, attn1, attn2, partials);
    context_reduce_kernel<<<dim3(64), 256, 0, stream>>>(partials, c_t);
}